// Round 1
// baseline (65.225 us; speedup 1.0000x reference)
//
#include <hip/hip_runtime.h>

// Grid: 100x100 pixels, 9 channels. Input abu: (10000, 9) float32, row-major
// (channel fastest). Output: scalar float32.
//
// loss = sum_c S2[c] / (sqrt(S1[c]) + 1e-4)
//   S1[c] = sum_i abu[i,c]^2
//   S2[c] = sum_i | stencil(abu)[i,c] * abu[i,c] |
// stencil = (sum 4 straight + (sum 4 diag)/sqrt2) / (4/sqrt2 + 4), zero-padded.

#define HH 100
#define WW 100
#define CC 9
#define NPIX (HH * WW)

__global__ __launch_bounds__(256) void k_partials(const float* __restrict__ abu,
                                                  float* __restrict__ ws) {
    const float INV_SQRT2 = 0.70710678118654752440f;
    const float INV_DENOM = 1.0f / 6.82842712474619009760f;  // 1/(4/sqrt2+4)

    int p = blockIdx.x * blockDim.x + threadIdx.x;

    float sq[CC];
    float pr[CC];

    if (p < NPIX) {
        int h = p / WW;
        int w = p - h * WW;
        const int base = p * CC;
        const bool up = (h > 0), dn = (h < HH - 1);
        const bool lf = (w > 0), rt = (w < WW - 1);

        const int oU = -WW * CC, oD = WW * CC, oL = -CC, oR = CC;

#pragma unroll
        for (int c = 0; c < CC; ++c) {
            float s = 0.0f;
            float d = 0.0f;
            if (up) s += abu[base + oU + c];
            if (dn) s += abu[base + oD + c];
            if (lf) s += abu[base + oL + c];
            if (rt) s += abu[base + oR + c];
            if (up && lf) d += abu[base + oU + oL + c];
            if (up && rt) d += abu[base + oU + oR + c];
            if (dn && lf) d += abu[base + oD + oL + c];
            if (dn && rt) d += abu[base + oD + oR + c];
            float st = (s + d * INV_SQRT2) * INV_DENOM;
            float cen = abu[base + c];
            sq[c] = cen * cen;
            pr[c] = fabsf(st * cen);
        }
    } else {
#pragma unroll
        for (int c = 0; c < CC; ++c) { sq[c] = 0.0f; pr[c] = 0.0f; }
    }

    __shared__ float part[2 * CC];
    if (threadIdx.x < 2 * CC) part[threadIdx.x] = 0.0f;
    __syncthreads();

    // Wave (64-lane) butterfly reduce per channel, then one LDS atomic per wave.
#pragma unroll
    for (int c = 0; c < CC; ++c) {
        float a = sq[c];
        float b = pr[c];
#pragma unroll
        for (int off = 32; off > 0; off >>= 1) {
            a += __shfl_down(a, off);
            b += __shfl_down(b, off);
        }
        if ((threadIdx.x & 63) == 0) {
            atomicAdd(&part[c], a);
            atomicAdd(&part[CC + c], b);
        }
    }
    __syncthreads();

    if (threadIdx.x < 2 * CC) atomicAdd(&ws[threadIdx.x], part[threadIdx.x]);
}

__global__ __launch_bounds__(64) void k_final(const float* __restrict__ ws,
                                              float* __restrict__ out) {
    int c = threadIdx.x;
    float v = 0.0f;
    if (c < CC) {
        float s1 = ws[c];
        float s2 = ws[CC + c];
        v = s2 / (sqrtf(s1) + 1e-4f);
    }
    // lanes 9..63 hold 0; offsets 8,4,2,1 gather lanes 0..15 into lane 0
#pragma unroll
    for (int off = 8; off > 0; off >>= 1) v += __shfl_down(v, off);
    if (threadIdx.x == 0) out[0] = v;
}

extern "C" void kernel_launch(void* const* d_in, const int* in_sizes, int n_in,
                              void* d_out, int out_size, void* d_ws, size_t ws_size,
                              hipStream_t stream) {
    const float* abu = (const float*)d_in[0];
    float* out = (float*)d_out;
    float* ws = (float*)d_ws;

    hipMemsetAsync(ws, 0, 2 * CC * sizeof(float), stream);

    int nblocks = (NPIX + 255) / 256;  // 40
    k_partials<<<nblocks, 256, 0, stream>>>(abu, ws);
    k_final<<<1, 64, 0, stream>>>(ws, out);
}